// Round 10
// baseline (969.758 us; speedup 1.0000x reference)
//
#include <hip/hip_runtime.h>
#include <cmath>
#include <cstddef>

// ACT cell, B=4096 D=512 H=1024 O=512 MAX_ITER=10 EPS=0.01
//
// GEMMs: bf16 MFMA split-3 fp32 emulation (hi*hi + hi*lo + lo*hi), K'=3K.
// Round 10:
//  - XCD swizzle fixed: XCD owns 8 contiguous bx panels x all by
//    (A panel 2 MB L2-resident; round 9's mapping streamed all of A per XCD).
//  - xproj back to f32 (bf16 split saved no bytes, cost 4x absmax).
//  - halt(t-1) fused into MODE1(t) dispatch as 64 prepended blocks.
//  - y = s_acc @ Wans^T + P*b_ans (one GEMM); 3-deep counted-vmcnt pipeline.

#define MAX_ITER 10

typedef short bf16x8 __attribute__((ext_vector_type(8)));
typedef float f32x4  __attribute__((ext_vector_type(4)));

__device__ __forceinline__ ushort f2bf(float f) {
    unsigned u = __float_as_uint(f);
    u += 0x7fff + ((u >> 16) & 1);          // RNE
    return (ushort)(u >> 16);
}
__device__ __forceinline__ float bf2f(ushort b) {
    return __uint_as_float(((unsigned)b) << 16);
}
__device__ __forceinline__ void gld16(const void* g, void* l) {
    __builtin_amdgcn_global_load_lds(
        (const __attribute__((address_space(1))) void*)g,
        (__attribute__((address_space(3))) void*)l, 16, 0, 0);
}

// XCD-aware block map: XCD (b&7) owns bx in [x*c,(x+1)*c), c=gx/8; by fast.
__device__ __forceinline__ void xcd_map(int b, int gx, int& bx, int& by) {
    const int c = gx >> 3;
    const int l = b >> 3;
    bx = (b & 7) * c + (l % c);
    by = l / c;
}

// ---------------------------------------------------------------------------
// MODE 0: Cout = acc + e0[col] + e1[col]                  (xproj, f32 out)
// MODE 1: s = tanh(acc + e0[row*ldn+col] + flag*e1[col]); write split(s)
// MODE 3: Cout[rc] = acc + e1[row]*e0[col]                (final y)
// 256 threads, 4 waves 2x2; 3-buffer LDS; counted-vmcnt pipeline.
// ---------------------------------------------------------------------------
template<int BM, int BN, int MODE>
__device__ __forceinline__ void gemm_body(
    int bx, int by,
    const ushort* __restrict__ ahi, const ushort* __restrict__ alo, int lda,
    const ushort* __restrict__ bhi, const ushort* __restrict__ blo, int ldb,
    int tps, float* __restrict__ Cout, int ldn,
    const float* __restrict__ e0, const float* __restrict__ e1, float flag,
    ushort* __restrict__ shiO, ushort* __restrict__ sloO,
    ushort* smem)
{
    constexpr int FRM = BM / 32;
    constexpr int FRN = BN / 32;
    constexpr int NL  = (BM + BN) / 32;      // global_load_lds per thread/stage
    ushort* As = smem;                        // [3][BM*64]
    ushort* Bs = smem + 3 * BM * 64;          // [3][BN*64]

    const int tid  = threadIdx.x;
    const int lane = tid & 63;
    const int wave = tid >> 6;
    const int lq   = lane & 15;
    const int kh   = lane >> 4;
    const int wr0  = (wave >> 1) * (BM / 2);
    const int wc0  = (wave & 1) * (BN / 2);
    const int m0   = bx * BM;
    const int n0   = by * BN;

    f32x4 acc[FRM][FRN];
#pragma unroll
    for (int r = 0; r < FRM; ++r)
#pragma unroll
        for (int c = 0; c < FRN; ++c) acc[r][c] = (f32x4)0.f;

    const int steps = 3 * tps;

    auto stage = [&](int buf, int t) {
        const int seg = (t >= 2 * tps) ? 2 : ((t >= tps) ? 1 : 0);
        const int k0  = (t - seg * tps) * 64;
        const ushort* aS = (seg == 2) ? alo : ahi;
        const ushort* bS = (seg == 1) ? blo : bhi;
#pragma unroll
        for (int j = 0; j < BM / 32; ++j) {
            int c   = j * 256 + tid;
            int row = c >> 3;                       // 8 x 16B chunks per 128B row
            int kb  = ((c & 7) << 4) ^ ((row & 7) << 4);
            gld16(aS + (size_t)(m0 + row) * lda + k0 + (kb >> 1),
                  As + buf * (BM * 64) + (size_t)(j * 256 + (tid & ~63)) * 8);
        }
#pragma unroll
        for (int j = 0; j < BN / 32; ++j) {
            int c   = j * 256 + tid;
            int row = c >> 3;
            int kb  = ((c & 7) << 4) ^ ((row & 7) << 4);
            gld16(bS + (size_t)(n0 + row) * ldb + k0 + (kb >> 1),
                  Bs + buf * (BN * 64) + (size_t)(j * 256 + (tid & ~63)) * 8);
        }
    };

    stage(0, 0);
    stage(1, 1);
    stage(2, 2);                         // 3 tiles in flight

    int cur = 0;
    for (int t = 0; t < steps; ++t) {
        const int rem = steps - 1 - t;
        if (rem >= 2)      __builtin_amdgcn_s_waitcnt(0xF70 | (2 * NL));
        else if (rem == 1) __builtin_amdgcn_s_waitcnt(0xF70 | NL);
        else               __builtin_amdgcn_s_waitcnt(0xF70);
        __builtin_amdgcn_sched_barrier(0);
        __builtin_amdgcn_s_barrier();        // all waves' stage(t) landed
        __builtin_amdgcn_sched_barrier(0);

        const ushort* Ab = As + cur * (BM * 64);
        const ushort* Bb = Bs + cur * (BN * 64);
#pragma unroll
        for (int kt = 0; kt < 2; ++kt) {
            bf16x8 af[FRM], bfr[FRN];
#pragma unroll
            for (int r = 0; r < FRM; ++r) {
                int row = wr0 + r * 16 + lq;
                int kb  = (kt * 64 + kh * 16) ^ ((row & 7) << 4);
                af[r] = *reinterpret_cast<const bf16x8*>(&Ab[row * 64 + (kb >> 1)]);
            }
#pragma unroll
            for (int c = 0; c < FRN; ++c) {
                int row = wc0 + c * 16 + lq;
                int kb  = (kt * 64 + kh * 16) ^ ((row & 7) << 4);
                bfr[c] = *reinterpret_cast<const bf16x8*>(&Bb[row * 64 + (kb >> 1)]);
            }
            __builtin_amdgcn_s_setprio(1);
#pragma unroll
            for (int r = 0; r < FRM; ++r)
#pragma unroll
                for (int c = 0; c < FRN; ++c)
                    acc[r][c] = __builtin_amdgcn_mfma_f32_16x16x32_bf16(
                        af[r], bfr[c], acc[r][c], 0, 0, 0);
            __builtin_amdgcn_s_setprio(0);
        }
        __builtin_amdgcn_sched_barrier(0);
        __builtin_amdgcn_s_barrier();        // all waves done reading buf[cur]
        __builtin_amdgcn_sched_barrier(0);
        if (t + 3 < steps) stage(cur, t + 3);   // overwrite now safe
        cur = (cur == 2) ? 0 : cur + 1;
    }

    // epilogue — C/D layout: col = lane&15, row = (lane>>4)*4 + q  [m89]
#pragma unroll
    for (int r = 0; r < FRM; ++r)
#pragma unroll
        for (int c = 0; c < FRN; ++c) {
            const size_t col = n0 + wc0 + c * 16 + lq;
#pragma unroll
            for (int q = 0; q < 4; ++q) {
                const size_t row = m0 + wr0 + r * 16 + kh * 4 + q;
                float v = acc[r][c][q];
                if constexpr (MODE == 0) {
                    Cout[row * ldn + col] = v + e0[col] + e1[col];
                } else if constexpr (MODE == 1) {
                    v += e0[row * ldn + col];
                    if (flag != 0.f) v += flag * e1[col];
                    float s = tanhf(v);
                    ushort hb = f2bf(s);
                    ushort lb = f2bf(s - bf2f(hb));
                    shiO[row * ldn + col] = hb;
                    sloO[row * ldn + col] = lb;
                } else {                      // MODE 3
                    Cout[row * ldn + col] = v + e1[row] * e0[col];
                }
            }
        }
}

template<int BM, int BN, int MODE>
__global__ __launch_bounds__(256)
void mfma_gemm(int gx,
               const ushort* __restrict__ ahi, const ushort* __restrict__ alo, int lda,
               const ushort* __restrict__ bhi, const ushort* __restrict__ blo, int ldb,
               int tps, float* __restrict__ Cout, int ldn,
               const float* __restrict__ e0, const float* __restrict__ e1,
               float flag, ushort* __restrict__ shiO, ushort* __restrict__ sloO)
{
    __shared__ __align__(16) ushort smem[3 * (BM + BN) * 64];
    int bx, by;
    xcd_map(blockIdx.x, gx, bx, by);
    gemm_body<BM, BN, MODE>(bx, by, ahi, alo, lda, bhi, blo, ldb,
                            tps, Cout, ldn, e0, e1, flag, shiO, sloO, smem);
}

// ---------------------------------------------------------------------------
// halt rows [blk*64, blk*64+64): 4 lanes/row, shfl-reduced dot, per-row ACT
// state machine, s_acc += p*s.  (reads-before-writes within lockstep wave)
// ---------------------------------------------------------------------------
__device__ __forceinline__ void halt_rows(
    int blk,
    const ushort* __restrict__ shi, const ushort* __restrict__ slo,
    const float* __restrict__ Whalt, const float* __restrict__ bhalt,
    float* __restrict__ hA, float* __restrict__ rA, float* __restrict__ RA,
    float* __restrict__ NA, float* __restrict__ stA, float* __restrict__ pAcc,
    float* __restrict__ s_acc, float n1, int H)
{
    const int tid = threadIdx.x;
    const int row = blk * 64 + (tid >> 2);
    const int c0  = (tid & 3) * (H / 4);
    const size_t base = (size_t)row * H + c0;

    float dot = 0.f;
    for (int i = 0; i < H / 4; i += 4) {
        ushort4 h4 = *reinterpret_cast<const ushort4*>(shi + base + i);
        ushort4 l4 = *reinterpret_cast<const ushort4*>(slo + base + i);
        float4  w4 = *reinterpret_cast<const float4*>(Whalt + c0 + i);
        dot += (bf2f(h4.x) + bf2f(l4.x)) * w4.x + (bf2f(h4.y) + bf2f(l4.y)) * w4.y
             + (bf2f(h4.z) + bf2f(l4.z)) * w4.z + (bf2f(h4.w) + bf2f(l4.w)) * w4.w;
    }
    dot += __shfl_xor(dot, 1, 64);
    dot += __shfl_xor(dot, 2, 64);       // all 4 lanes of the row hold full dot

    float h_n = 1.f / (1.f + expf(-(dot + bhalt[0])));
    float hh  = hA[row] + h_n;
    bool  isN = hh >= 0.99f;             // 1 - EPS
    float pv  = isN ? rA[row] : h_n;
    float r_new = isN ? 0.f : 1.f - hh;
    if ((tid & 3) == 0) {
        if (!isN) { RA[row] = r_new; NA[row] = n1; stA[row] += 1.f; }
        hA[row] = hh; rA[row] = r_new; pAcc[row] += pv;
    }
    if (pv != 0.f) {
        for (int i = 0; i < H / 4; i += 4) {
            ushort4 h4 = *reinterpret_cast<const ushort4*>(shi + base + i);
            ushort4 l4 = *reinterpret_cast<const ushort4*>(slo + base + i);
            float4 o = *reinterpret_cast<float4*>(s_acc + base + i);
            o.x = fmaf(pv, bf2f(h4.x) + bf2f(l4.x), o.x);
            o.y = fmaf(pv, bf2f(h4.y) + bf2f(l4.y), o.y);
            o.z = fmaf(pv, bf2f(h4.z) + bf2f(l4.z), o.z);
            o.w = fmaf(pv, bf2f(h4.w) + bf2f(l4.w), o.w);
            *reinterpret_cast<float4*>(s_acc + base + i) = o;
        }
    }
}

// blocks [0, hblks): halt(t-1) on s_cur; blocks [hblks, +512): MODE1(t).
__global__ __launch_bounds__(256)
void merged_step(int hblks, int gx,
                 const ushort* __restrict__ s_hi, const ushort* __restrict__ s_lo,
                 const ushort* __restrict__ whhhi, const ushort* __restrict__ whhlo,
                 int H, int tps,
                 const float* __restrict__ xproj, const float* __restrict__ wcol,
                 ushort* __restrict__ o_hi, ushort* __restrict__ o_lo,
                 const float* __restrict__ Whalt, const float* __restrict__ bhalt,
                 float* __restrict__ hA, float* __restrict__ rA, float* __restrict__ RA,
                 float* __restrict__ NA, float* __restrict__ stA,
                 float* __restrict__ pAcc, float* __restrict__ s_acc, float n1)
{
    extern __shared__ ushort smem[];
    const int b = blockIdx.x;
    if (b < hblks) {
        halt_rows(b, s_hi, s_lo, Whalt, bhalt, hA, rA, RA, NA, stA, pAcc,
                  s_acc, n1, H);
    } else {
        int bx, by;
        xcd_map(b - hblks, gx, bx, by);
        gemm_body<64, 128, 1>(bx, by, s_hi, s_lo, H, whhhi, whhlo, H, tps,
                              nullptr, H, xproj, wcol, 0.f, o_hi, o_lo, smem);
    }
}

// ---------------------------------------------------------------------------
__global__ void init_kernel(float* __restrict__ sacc_zero, size_t nzero,
                            float* __restrict__ hA, float* __restrict__ rA,
                            float* __restrict__ RA, float* __restrict__ NA,
                            float* __restrict__ stA, float* __restrict__ pAcc,
                            const float* __restrict__ prev_steps, int B)
{
    size_t i = (size_t)blockIdx.x * 256 + threadIdx.x;
    if (i < nzero) sacc_zero[i] = 0.f;
    if (i < (size_t)B) {
        hA[i] = 0.f; rA[i] = 1.f; RA[i] = 1.f; NA[i] = 0.f;
        stA[i] = prev_steps[i] + 1.f; pAcc[i] = 0.f;
    }
}

__global__ void split_f32(const float* __restrict__ src,
                          ushort* __restrict__ hi, ushort* __restrict__ lo, size_t n4)
{
    size_t i = (size_t)blockIdx.x * 256 + threadIdx.x;
    if (i < n4) {
        float4 v = reinterpret_cast<const float4*>(src)[i];
        ushort4 h, l;
        h.x = f2bf(v.x); l.x = f2bf(v.x - bf2f(h.x));
        h.y = f2bf(v.y); l.y = f2bf(v.y - bf2f(h.y));
        h.z = f2bf(v.z); l.z = f2bf(v.z - bf2f(h.z));
        h.w = f2bf(v.w); l.w = f2bf(v.w - bf2f(h.w));
        reinterpret_cast<ushort4*>(hi)[i] = h;
        reinterpret_cast<ushort4*>(lo)[i] = l;
    }
}

// W_ih[H, D+1] -> split [H,D] + wcol[H]
__global__ void wih_split(const float* __restrict__ Wih,
                          ushort* __restrict__ hi, ushort* __restrict__ lo,
                          float* __restrict__ wcol, int H, int D)
{
    size_t i = (size_t)blockIdx.x * 256 + threadIdx.x;
    if (i < (size_t)H * D) {
        int h = (int)(i / D), d = (int)(i % D);
        float v = Wih[(size_t)h * (D + 1) + d];
        ushort hb = f2bf(v);
        hi[i] = hb; lo[i] = f2bf(v - bf2f(hb));
    }
    if (i < (size_t)H) wcol[i] = Wih[i * (size_t)(D + 1) + D];
}

// final halt (step MAX_ITER-1): p = r; s_acc += r*s; P += r; split(s_acc).
__global__ __launch_bounds__(256)
void final_halt(const ushort* __restrict__ shi, const ushort* __restrict__ slo,
                const float* __restrict__ rA, float* __restrict__ pAcc,
                float* __restrict__ s_acc,
                ushort* __restrict__ fsHi, ushort* __restrict__ fsLo, int H)
{
    const int b = blockIdx.x;
    const int tid = threadIdx.x;
    const size_t base = (size_t)b * H;
    const int i = tid * 4;                     // H == 1024 == 256*4
    const float pv = rA[b];
    if (tid == 0) pAcc[b] += pv;
    ushort4 h4 = *reinterpret_cast<const ushort4*>(shi + base + i);
    ushort4 l4 = *reinterpret_cast<const ushort4*>(slo + base + i);
    float4 o = *reinterpret_cast<const float4*>(s_acc + base + i);
    o.x = fmaf(pv, bf2f(h4.x) + bf2f(l4.x), o.x);
    o.y = fmaf(pv, bf2f(h4.y) + bf2f(l4.y), o.y);
    o.z = fmaf(pv, bf2f(h4.z) + bf2f(l4.z), o.z);
    o.w = fmaf(pv, bf2f(h4.w) + bf2f(l4.w), o.w);
    *reinterpret_cast<float4*>(s_acc + base + i) = o;
    ushort4 fh, fl;
    fh.x = f2bf(o.x); fl.x = f2bf(o.x - bf2f(fh.x));
    fh.y = f2bf(o.y); fl.y = f2bf(o.y - bf2f(fh.y));
    fh.z = f2bf(o.z); fl.z = f2bf(o.z - bf2f(fh.z));
    fh.w = f2bf(o.w); fl.w = f2bf(o.w - bf2f(fh.w));
    *reinterpret_cast<ushort4*>(fsHi + base + i) = fh;
    *reinterpret_cast<ushort4*>(fsLo + base + i) = fl;
}

__global__ void finalize_kernel(const float* __restrict__ pp, const float* __restrict__ RA,
                                const float* __restrict__ NA, const float* __restrict__ stA,
                                float* __restrict__ pon, float* __restrict__ stp, int B)
{
    int i = blockIdx.x * 256 + threadIdx.x;
    if (i < B) { pon[i] = pp[i] + RA[i] + NA[i]; stp[i] = stA[i]; }
}

// ---------------------------------------------------------------------------
extern "C" void kernel_launch(void* const* d_in, const int* in_sizes, int n_in,
                              void* d_out, int out_size, void* d_ws, size_t ws_size,
                              hipStream_t stream)
{
    const float* x     = (const float*)d_in[0];
    const float* ph    = (const float*)d_in[1];
    const float* pp    = (const float*)d_in[2];
    const float* ps    = (const float*)d_in[3];
    const float* Wih   = (const float*)d_in[4];
    const float* bih   = (const float*)d_in[5];
    const float* Whh   = (const float*)d_in[6];
    const float* bhh   = (const float*)d_in[7];
    const float* Whalt = (const float*)d_in[8];
    const float* bhalt = (const float*)d_in[9];
    const float* Wans  = (const float*)d_in[10];
    const float* bans  = (const float*)d_in[11];

    const int B = in_sizes[2];
    const int H = in_sizes[5];
    const int O = in_sizes[11];
    const int D = in_sizes[0] / B;

    float* out_y   = (float*)d_out;
    float* out_sac = out_y + (size_t)B * O;
    float* out_pon = out_sac + (size_t)B * H;
    float* out_stp = out_pon + B;

    // workspace layout (16B-aligned chunks)
    char* w = (char*)d_ws;
    float* xproj = (float*)w;  w += (size_t)B * H * 4;
    ushort* shi[2], *slo[2];
    shi[0] = (ushort*)w; w += (size_t)B * H * 2;
    slo[0] = (ushort*)w; w += (size_t)B * H * 2;
    shi[1] = (ushort*)w; w += (size_t)B * H * 2;
    slo[1] = (ushort*)w; w += (size_t)B * H * 2;
    ushort* whhhi = (ushort*)w; w += (size_t)H * H * 2;
    ushort* whhlo = (ushort*)w; w += (size_t)H * H * 2;
    ushort* wanshi = (ushort*)w; w += (size_t)O * H * 2;
    ushort* wanslo = (ushort*)w; w += (size_t)O * H * 2;
    ushort* wihhi = (ushort*)w; w += (size_t)H * D * 2;
    ushort* wihlo = (ushort*)w; w += (size_t)H * D * 2;
    float* wcol = (float*)w; w += (size_t)H * 4;
    float* hA   = (float*)w; w += (size_t)B * 4;
    float* rA   = (float*)w; w += (size_t)B * 4;
    float* RA   = (float*)w; w += (size_t)B * 4;
    float* NA   = (float*)w; w += (size_t)B * 4;
    float* stA  = (float*)w; w += (size_t)B * 4;
    float* pAcc = (float*)w; w += (size_t)B * 4;

    // x split aliases s[1] (dead before s[1] first written at t=0 MODE1);
    // s_acc split aliases xproj (xproj last read by MODE1 t=9, which runs
    // before the final halt writes these — stream-ordered).
    ushort* xhi = shi[1];
    ushort* xlo = slo[1];
    ushort* sacHi = (ushort*)xproj;
    ushort* sacLo = sacHi + (size_t)B * H;

    init_kernel<<<(unsigned)(((size_t)B * H + 255) / 256), 256, 0, stream>>>(
        out_sac, (size_t)B * H, hA, rA, RA, NA, stA, pAcc, ps, B);

    split_f32<<<(unsigned)(((size_t)B * D / 4 + 255) / 256), 256, 0, stream>>>(x, xhi, xlo, (size_t)B * D / 4);
    split_f32<<<(unsigned)(((size_t)B * H / 4 + 255) / 256), 256, 0, stream>>>(ph, shi[0], slo[0], (size_t)B * H / 4);
    split_f32<<<(unsigned)(((size_t)H * H / 4 + 255) / 256), 256, 0, stream>>>(Whh, whhhi, whhlo, (size_t)H * H / 4);
    split_f32<<<(unsigned)(((size_t)O * H / 4 + 255) / 256), 256, 0, stream>>>(Wans, wanshi, wanslo, (size_t)O * H / 4);
    wih_split<<<(unsigned)(((size_t)H * D + 255) / 256), 256, 0, stream>>>(Wih, wihhi, wihlo, wcol, H, D);

    // xproj = x @ W_ih[:, :D]^T + b_ih + b_hh   (f32)
    mfma_gemm<64, 128, 0><<<(B / 64) * (H / 128), 256, 0, stream>>>(
        B / 64, xhi, xlo, D, wihhi, wihlo, D, D / 64,
        xproj, H, bih, bhh, 0.f, nullptr, nullptr);

    // step 0: MODE1 with flag=1
    mfma_gemm<64, 128, 1><<<(B / 64) * (H / 128), 256, 0, stream>>>(
        B / 64, shi[0], slo[0], H, whhhi, whhlo, H, H / 64,
        nullptr, H, xproj, wcol, 1.f, shi[1], slo[1]);

    const int hblks = B / 64;                        // 64 halt blocks
    const int gblks = (B / 64) * (H / 128);          // 512 GEMM blocks
    const size_t lds_m = 3u * (64 + 128) * 64 * sizeof(ushort);   // 72 KB

    int cur = 1;   // s after step 0 lives in buffer 1
    for (int t = 1; t < MAX_ITER; t++) {
        // halt(step t-1) [n = t+1] fused with MODE1(step t): s[cur] -> s[cur^1]
        merged_step<<<hblks + gblks, 256, lds_m, stream>>>(
            hblks, B / 64, shi[cur], slo[cur], whhhi, whhlo, H, H / 64,
            xproj, wcol, shi[cur ^ 1], slo[cur ^ 1],
            Whalt, bhalt, hA, rA, RA, NA, stA, pAcc, out_sac, (float)(t + 1));
        cur ^= 1;
    }

    // final halt (step 9): p = r, s_acc += r*s, P += r, write split(s_acc)
    final_halt<<<B, 256, 0, stream>>>(
        shi[cur], slo[cur], rA, pAcc, out_sac, sacHi, sacLo, H);

    // y = s_acc @ Wans^T + P * b_ans   (single GEMM, full write)
    mfma_gemm<64, 64, 3><<<(B / 64) * (O / 64), 256, 0, stream>>>(
        B / 64, sacHi, sacLo, H, wanshi, wanslo, H, H / 64,
        out_y, O, bans, pAcc, 0.f, nullptr, nullptr);

    finalize_kernel<<<(B + 255) / 256, 256, 0, stream>>>(
        pp, RA, NA, stA, out_pon, out_stp, B);
}